// Round 2
// baseline (813.226 us; speedup 1.0000x reference)
//
#include <hip/hip_runtime.h>
#include <math.h>

#define BS 256
#define V 10475
#define NJ 55
#define R3 31425      // V*3
#define NP 486        // 54*9
#define LB 60         // effective betas (10 shape + 50 expression)
#define JOFF 8044800  // BS*R3 — joints output offset

__device__ const int PARENTS_d[NJ] = {
  -1, 0, 0, 0, 1, 2, 3, 4, 5, 6, 7, 8, 9, 9, 9, 12, 13, 14, 16, 17, 18, 19,
  15, 15, 15, 20, 25, 26, 20, 28, 29, 20, 31, 32, 20, 34, 35, 20, 37, 38,
  21, 40, 41, 21, 43, 44, 21, 46, 47, 21, 49, 50, 21, 52, 53
};

// ---------------- K1: rodrigues + F rows ([pf(486) ; betas(60)] x 256) ----
__global__ __launch_bounds__(256) void k_pose(
    const float* __restrict__ pose, const float* __restrict__ shp,
    const float* __restrict__ expr, const float* __restrict__ go,
    float* __restrict__ rot_ws, float* __restrict__ pf_T,
    float* __restrict__ betas_T) {
  int b = threadIdx.x;
  int j = blockIdx.x;
  if (j == NJ) {  // betas builder block
    #pragma unroll
    for (int l = 0; l < 10; ++l) betas_T[l * BS + b] = shp[b * 10 + l];
    #pragma unroll
    for (int l = 0; l < 50; ++l) betas_T[(10 + l) * BS + b] = expr[b * 50 + l];
    return;
  }
  float rx, ry, rz;
  if (j == 0) { rx = go[0]; ry = go[1]; rz = go[2]; }
  else if (j == 23 || j == 24) { rx = 0.f; ry = 0.f; rz = 0.f; }
  else {
    int src = (j <= 21) ? j : (j == 22 ? 52 : j - 3);
    const float* p = pose + ((size_t)b * 53 + src) * 3;
    rx = p[0]; ry = p[1]; rz = p[2];
  }
  float sx = rx + 1e-8f, sy = ry + 1e-8f, sz = rz + 1e-8f;
  float ang = sqrtf(sx * sx + sy * sy + sz * sz);
  float inv = 1.f / ang;
  float x = rx * inv, y = ry * inv, z = rz * inv;
  float s = sinf(ang), c = cosf(ang), C = 1.f - c;
  float R[9];
  R[0] = 1.f - C * (y * y + z * z);
  R[1] = -s * z + C * x * y;
  R[2] =  s * y + C * x * z;
  R[3] =  s * z + C * x * y;
  R[4] = 1.f - C * (x * x + z * z);
  R[5] = -s * x + C * y * z;
  R[6] = -s * y + C * x * z;
  R[7] =  s * x + C * y * z;
  R[8] = 1.f - C * (x * x + y * y);
  float* rw = rot_ws + ((size_t)b * NJ + j) * 9;
  #pragma unroll
  for (int e = 0; e < 9; ++e) rw[e] = R[e];
  if (j >= 1) {
    int pb = (j - 1) * 9;
    #pragma unroll
    for (int e = 0; e < 9; ++e)
      pf_T[(pb + e) * BS + b] = R[e] - ((e == 0 || e == 4 || e == 8) ? 1.f : 0.f);
  }
}

// ---------------- K1b: JregT[v][56] = Jreg[j][v] transpose ----------------
__global__ __launch_bounds__(256) void k_tr(
    const float* __restrict__ Jreg, float* __restrict__ JregT) {
  __shared__ float tile[NJ * 257];
  int tid = threadIdx.x;
  int vb = blockIdx.x * 256;
  #pragma unroll 1
  for (int j = 0; j < NJ; ++j) {
    int v = vb + tid;
    tile[j * 257 + tid] = (v < V) ? Jreg[(size_t)j * V + v] : 0.f;
  }
  __syncthreads();
  for (int idx = tid; idx < 256 * 56; idx += 256) {
    int vl = idx / 56, j = idx - vl * 56;
    int v = vb + vl;
    if (v < V) JregT[(size_t)v * 56 + j] = (j < NJ) ? tile[j * 257 + vl] : 0.f;
  }
}

// ---------------- K2: JS[j][c][61] — all j in registers, sd read 3x -------
__global__ __launch_bounds__(256) void k_js2(
    const float* __restrict__ JregT, const float* __restrict__ sd,
    const float* __restrict__ vt, float* __restrict__ JS) {
  int tid = threadIdx.x;
  int l = tid & 63;
  int g = tid >> 6;
  int c = blockIdx.x;
  int slot = blockIdx.y * 4 + g;     // 0..63
  int cidx = (l < 10) ? l : (290 + l);
  bool in60 = (l < 60), is60 = (l == 60);
  float acc[NJ];
  #pragma unroll
  for (int j = 0; j < NJ; ++j) acc[j] = 0.f;
  #pragma unroll 2
  for (int v = slot; v < V; v += 64) {
    int vu = __builtin_amdgcn_readfirstlane(v);
    float xv;
    if (in60)      xv = sd[((size_t)vu * 3 + c) * 350 + cidx];
    else if (is60) xv = vt[(size_t)vu * 3 + c];
    else           xv = 0.f;
    const float* __restrict__ Jr = JregT + (size_t)vu * 56;  // uniform → s_load
    #pragma unroll
    for (int j = 0; j < NJ; ++j) acc[j] += Jr[j] * xv;
  }
  __shared__ float red[NJ * 64];
  for (int idx = tid; idx < NJ * 64; idx += 256) red[idx] = 0.f;
  __syncthreads();
  #pragma unroll
  for (int j = 0; j < NJ; ++j) atomicAdd(&red[j * 64 + l], acc[j]);
  __syncthreads();
  for (int idx = tid; idx < NJ * 61; idx += 256) {
    int j = idx / 61, ll = idx - j * 61;
    atomicAdd(&JS[(j * 3 + c) * 61 + ll], red[j * 64 + ll]);
  }
}

// ---------------- K3: joints + kinematic chain + A_rel --------------------
__global__ __launch_bounds__(64) void k_chain(
    const float* __restrict__ JS, const float* __restrict__ betas_T,
    const float* __restrict__ rot_ws, float* __restrict__ arel,
    float* __restrict__ out) {
  int b = blockIdx.x;
  int lane = threadIdx.x;
  __shared__ float joints_l[165];
  __shared__ float Tl[880];
  __shared__ float A[880];
  for (int idx = lane; idx < 165; idx += 64) {
    float sacc = JS[idx * 61 + 60];  // v_template column, beta = 1
    #pragma unroll
    for (int l = 0; l < LB; ++l) sacc += JS[idx * 61 + l] * betas_T[l * BS + b];
    joints_l[idx] = sacc;
  }
  __syncthreads();
  for (int idx = lane; idx < 880; idx += 64) {
    int j = idx >> 4, e = idx & 15, r = e >> 2, c = e & 3;
    float val;
    if (r < 3) {
      if (c < 3) val = rot_ws[((size_t)b * NJ + j) * 9 + r * 3 + c];
      else {
        int par = PARENTS_d[j];
        val = joints_l[j * 3 + r] - (par >= 0 ? joints_l[par * 3 + r] : 0.f);
      }
    } else val = (c == 3) ? 1.f : 0.f;
    Tl[idx] = val;
  }
  __syncthreads();
  if (lane < 16) A[lane] = Tl[lane];
  __syncthreads();
  for (int j = 1; j < NJ; ++j) {
    int par = PARENTS_d[j];
    if (lane < 16) {
      int r = lane >> 2, c = lane & 3;
      float sacc = 0.f;
      #pragma unroll
      for (int k = 0; k < 4; ++k)
        sacc += A[par * 16 + r * 4 + k] * Tl[j * 16 + k * 4 + c];
      A[j * 16 + lane] = sacc;
    }
    __syncthreads();
  }
  for (int idx = lane; idx < 165; idx += 64) {
    int j = idx / 3, r = idx % 3;
    out[JOFF + (size_t)b * 165 + idx] = A[j * 16 + r * 4 + 3];
  }
  for (int idx = lane; idx < 660; idx += 64) {
    int j = idx / 12, e = idx % 12;
    float val;
    if (e < 9) { int r = e / 3, c = e % 3; val = A[j * 16 + r * 4 + c]; }
    else {
      int r = e - 9;
      val = A[j * 16 + r * 4 + 3]
          - (A[j * 16 + r * 4 + 0] * joints_l[j * 3 + 0] +
             A[j * 16 + r * 4 + 1] * joints_l[j * 3 + 1] +
             A[j * 16 + r * 4 + 2] * joints_l[j * 3 + 2]);
    }
    arel[(size_t)b * 660 + idx] = val;
  }
}

// ---------------- K4: GEMM  out[b][r] = vt[r] + sum_k F[k][b] * D[k][r] ---
// thread = row r (coalesced D loads), acc[128] batches, F rows via s_loads
__global__ __launch_bounds__(256) void k_gemm(
    const float* __restrict__ vt, const float* __restrict__ sd,
    const float* __restrict__ pd, const float* __restrict__ F,
    float* __restrict__ out) {
  int r = blockIdx.x * 256 + threadIdx.x;
  int rr = (r < R3) ? r : (R3 - 1);
  int b0 = blockIdx.y * 128;
  float acc[128];
  #pragma unroll
  for (int j = 0; j < 128; ++j) acc[j] = 0.f;

  // ---- pose part: K = 486 = 81*6, 6-deep prefetch ring ----
  float dbuf[6];
  #pragma unroll
  for (int u = 0; u < 6; ++u) dbuf[u] = pd[(size_t)u * R3 + rr];
  #pragma unroll 1
  for (int it = 0; it < 81; ++it) {
    int kn = (it + 1) * 6;
    float dn[6];
    #pragma unroll
    for (int u = 0; u < 6; ++u) {
      int kl = kn + u; kl = (kl < NP) ? kl : (NP - 1);
      dn[u] = pd[(size_t)kl * R3 + rr];
    }
    #pragma unroll
    for (int u = 0; u < 6; ++u) {
      const float* __restrict__ Frow = F + (size_t)(it * 6 + u) * BS + b0;
      float dv = dbuf[u];
      #pragma unroll
      for (int j = 0; j < 128; ++j) acc[j] += Frow[j] * dv;
    }
    #pragma unroll
    for (int u = 0; u < 6; ++u) dbuf[u] = dn[u];
  }

  // ---- shape part: K = 60 = 10*6, cols {0..9, 300..349} of sd row rr ----
  const float* __restrict__ sdr = sd + (size_t)rr * 350;
  #pragma unroll
  for (int u = 0; u < 6; ++u) dbuf[u] = sdr[u];
  #pragma unroll 1
  for (int it = 0; it < 10; ++it) {
    int kn = (it + 1) * 6;
    float dn[6];
    #pragma unroll
    for (int u = 0; u < 6; ++u) {
      int kl = kn + u; kl = (kl < LB) ? kl : (LB - 1);
      int cidx = (kl < 10) ? kl : (290 + kl);
      dn[u] = sdr[cidx];
    }
    #pragma unroll
    for (int u = 0; u < 6; ++u) {
      const float* __restrict__ Frow = F + (size_t)(NP + it * 6 + u) * BS + b0;
      float dv = dbuf[u];
      #pragma unroll
      for (int j = 0; j < 128; ++j) acc[j] += Frow[j] * dv;
    }
    #pragma unroll
    for (int u = 0; u < 6; ++u) dbuf[u] = dn[u];
  }

  float vtr = vt[rr];
  if (r < R3) {
    #pragma unroll
    for (int j = 0; j < 128; ++j)
      out[(size_t)(b0 + j) * R3 + r] = acc[j] + vtr;
  }
}

// ---------------- K5: skinning (reads v_posed from d_out in place) --------
__global__ __launch_bounds__(256) void k_skin(
    const float* __restrict__ lbs, const float* __restrict__ arel,
    float* __restrict__ out) {
  int v = blockIdx.x * 256 + threadIdx.x;
  bool valid = v < V;
  float w[NJ];
  if (valid) {
    #pragma unroll
    for (int j = 0; j < NJ; ++j) w[j] = lbs[(size_t)v * NJ + j];
  }
  int b0 = blockIdx.y * 4;
  for (int bi = 0; bi < 4; ++bi) {
    int b = b0 + bi;
    const float* __restrict__ ar = arel + (size_t)b * 660;  // block-uniform → s_loads
    if (valid) {
      float T[12];
      #pragma unroll
      for (int e = 0; e < 12; ++e) T[e] = 0.f;
      for (int j = 0; j < NJ; ++j) {
        float wj = w[j];
        #pragma unroll
        for (int e = 0; e < 12; ++e) T[e] += wj * ar[j * 12 + e];
      }
      float* vp = out + (size_t)b * R3 + v * 3;
      float x = vp[0], y = vp[1], z = vp[2];
      vp[0] = T[0] * x + T[1] * y + T[2] * z + T[9];
      vp[1] = T[3] * x + T[4] * y + T[5] * z + T[10];
      vp[2] = T[6] * x + T[7] * y + T[8] * z + T[11];
    }
  }
}

extern "C" void kernel_launch(void* const* d_in, const int* in_sizes, int n_in,
                              void* d_out, int out_size, void* d_ws, size_t ws_size,
                              hipStream_t stream) {
  const float* pose = (const float*)d_in[0];
  const float* shp  = (const float*)d_in[1];
  const float* expr = (const float*)d_in[2];
  const float* go   = (const float*)d_in[3];
  const float* vt   = (const float*)d_in[4];
  const float* sd   = (const float*)d_in[5];
  const float* pd   = (const float*)d_in[6];
  const float* jr   = (const float*)d_in[7];
  const float* lbs  = (const float*)d_in[8];
  float* out = (float*)d_out;
  float* ws  = (float*)d_ws;

  float* F      = ws;                   // 546*256 = 139776 (pf rows 0..485, betas 486..545)
  float* rot_ws = F + 139776;           // 256*55*9  = 126720
  float* JS     = rot_ws + 126720;      // 165*61    = 10065 (pad 10080)
  float* arel   = JS + 10080;           // 256*55*12 = 168960
  float* JregT  = arel + 168960;        // 10475*56  = 586600
  // total ~4.13 MB of d_ws

  float* pf_T    = F;
  float* betas_T = F + (size_t)NP * BS;

  hipMemsetAsync(JS, 0, 10080 * sizeof(float), stream);
  k_pose<<<NJ + 1, 256, 0, stream>>>(pose, shp, expr, go, rot_ws, pf_T, betas_T);
  k_tr<<<41, 256, 0, stream>>>(jr, JregT);
  k_js2<<<dim3(3, 16), 256, 0, stream>>>(JregT, sd, vt, JS);
  k_chain<<<BS, 64, 0, stream>>>(JS, betas_T, rot_ws, arel, out);
  k_gemm<<<dim3(123, 2), 256, 0, stream>>>(vt, sd, pd, F, out);
  k_skin<<<dim3((V + 255) / 256, BS / 4), 256, 0, stream>>>(lbs, arel, out);
}

// Round 3
// 417.417 us; speedup vs baseline: 1.9482x; 1.9482x over previous
//
#include <hip/hip_runtime.h>
#include <math.h>

#define BS 256
#define V 10475
#define NJ 55
#define R3 31425      // V*3
#define NP 486        // 54*9
#define LB 60         // effective betas (10 shape + 50 expression)
#define KP 576        // padded K (486 pose + 60 shape, pad to mult of 32)
#define JOFF 8044800  // BS*R3 — joints output offset
#define VP 10480      // V padded to mult of 16

typedef __attribute__((ext_vector_type(8))) short short8;
typedef __attribute__((ext_vector_type(4))) float float4_;

__device__ const int PARENTS_d[NJ] = {
  -1, 0, 0, 0, 1, 2, 3, 4, 5, 6, 7, 8, 9, 9, 9, 12, 13, 14, 16, 17, 18, 19,
  15, 15, 15, 20, 25, 26, 20, 28, 29, 20, 31, 32, 20, 34, 35, 20, 37, 38,
  21, 40, 41, 21, 43, 44, 21, 46, 47, 21, 49, 50, 21, 52, 53
};

__device__ __forceinline__ unsigned short f2b(float f) {
  unsigned int u = __float_as_uint(f);
  unsigned int r = (u + 0x7FFFu + ((u >> 16) & 1u)) >> 16;
  return (unsigned short)r;
}

// ---------------- K1: rodrigues + Ftr bf16 [b][576] + betas_T fp32 --------
__global__ __launch_bounds__(256) void k_pose(
    const float* __restrict__ pose, const float* __restrict__ shp,
    const float* __restrict__ expr, const float* __restrict__ go,
    float* __restrict__ rot_ws, unsigned short* __restrict__ Ftr,
    float* __restrict__ betas_T) {
  int b = threadIdx.x;
  int j = blockIdx.x;
  if (j == NJ) {  // betas block: Ftr rows 486..575 + betas_T
    #pragma unroll
    for (int l = 0; l < 10; ++l) {
      float v = shp[b * 10 + l];
      betas_T[l * BS + b] = v;
      Ftr[(size_t)b * KP + NP + l] = f2b(v);
    }
    #pragma unroll
    for (int l = 0; l < 50; ++l) {
      float v = expr[b * 50 + l];
      betas_T[(10 + l) * BS + b] = v;
      Ftr[(size_t)b * KP + NP + 10 + l] = f2b(v);
    }
    #pragma unroll
    for (int l = NP + LB; l < KP; ++l) Ftr[(size_t)b * KP + l] = 0;
    return;
  }
  float rx, ry, rz;
  if (j == 0) { rx = go[0]; ry = go[1]; rz = go[2]; }
  else if (j == 23 || j == 24) { rx = 0.f; ry = 0.f; rz = 0.f; }
  else {
    int src = (j <= 21) ? j : (j == 22 ? 52 : j - 3);
    const float* p = pose + ((size_t)b * 53 + src) * 3;
    rx = p[0]; ry = p[1]; rz = p[2];
  }
  float sx = rx + 1e-8f, sy = ry + 1e-8f, sz = rz + 1e-8f;
  float ang = sqrtf(sx * sx + sy * sy + sz * sz);
  float inv = 1.f / ang;
  float x = rx * inv, y = ry * inv, z = rz * inv;
  float s = sinf(ang), c = cosf(ang), C = 1.f - c;
  float R[9];
  R[0] = 1.f - C * (y * y + z * z);
  R[1] = -s * z + C * x * y;
  R[2] =  s * y + C * x * z;
  R[3] =  s * z + C * x * y;
  R[4] = 1.f - C * (x * x + z * z);
  R[5] = -s * x + C * y * z;
  R[6] = -s * y + C * x * z;
  R[7] =  s * x + C * y * z;
  R[8] = 1.f - C * (x * x + y * y);
  float* rw = rot_ws + ((size_t)b * NJ + j) * 9;
  #pragma unroll
  for (int e = 0; e < 9; ++e) rw[e] = R[e];
  if (j >= 1) {
    int pb = (j - 1) * 9;
    #pragma unroll
    for (int e = 0; e < 9; ++e)
      Ftr[(size_t)b * KP + pb + e] =
          f2b(R[e] - ((e == 0 || e == 4 || e == 8) ? 1.f : 0.f));
  }
}

// ---------------- K1b: JregT[v][56] = Jreg[j][v] transpose ----------------
__global__ __launch_bounds__(256) void k_tr(
    const float* __restrict__ Jreg, float* __restrict__ JregT) {
  __shared__ float tile[NJ * 257];
  int tid = threadIdx.x;
  int vb = blockIdx.x * 256;
  #pragma unroll 1
  for (int j = 0; j < NJ; ++j) {
    int v = vb + tid;
    tile[j * 257 + tid] = (v < V) ? Jreg[(size_t)j * V + v] : 0.f;
  }
  __syncthreads();
  for (int idx = tid; idx < 256 * 56; idx += 256) {
    int vl = idx / 56, j = idx - vl * 56;
    int v = vb + vl;
    if (v < V) JregT[(size_t)v * 56 + j] = (j < NJ) ? tile[j * 257 + vl] : 0.f;
  }
}

// ---------------- K2: JS[j][c][61] — all j in registers -------------------
__global__ __launch_bounds__(256) void k_js2(
    const float* __restrict__ JregT, const float* __restrict__ sd,
    const float* __restrict__ vt, float* __restrict__ JS) {
  int tid = threadIdx.x;
  int l = tid & 63;
  int g = tid >> 6;
  int c = blockIdx.x;
  int slot = blockIdx.y * 4 + g;     // 0..127
  int cidx = (l < 10) ? l : (290 + l);
  bool in60 = (l < 60), is60 = (l == 60);
  float acc[NJ];
  #pragma unroll
  for (int j = 0; j < NJ; ++j) acc[j] = 0.f;
  #pragma unroll 2
  for (int v = slot; v < V; v += 128) {
    int vu = __builtin_amdgcn_readfirstlane(v);
    float xv;
    if (in60)      xv = sd[((size_t)vu * 3 + c) * 350 + cidx];
    else if (is60) xv = vt[(size_t)vu * 3 + c];
    else           xv = 0.f;
    const float* __restrict__ Jr = JregT + (size_t)vu * 56;  // uniform → s_load
    #pragma unroll
    for (int j = 0; j < NJ; ++j) acc[j] += Jr[j] * xv;
  }
  __shared__ float red[NJ * 64];
  for (int idx = tid; idx < NJ * 64; idx += 256) red[idx] = 0.f;
  __syncthreads();
  #pragma unroll
  for (int j = 0; j < NJ; ++j) atomicAdd(&red[j * 64 + l], acc[j]);
  __syncthreads();
  for (int idx = tid; idx < NJ * 61; idx += 256) {
    int j = idx / 61, ll = idx - j * 61;
    atomicAdd(&JS[(j * 3 + c) * 61 + ll], red[j * 64 + ll]);
  }
}

// ---------------- K2b: Dtr[r][576] bf16 = transpose([pd ; sd_slice]) ------
// tile 64k x 64r via LDS
__global__ __launch_bounds__(256) void k_trD(
    const float* __restrict__ pd, const float* __restrict__ sd,
    unsigned short* __restrict__ Dtr) {
  __shared__ float tile[64 * 68];
  int t = threadIdx.x;
  int rt = blockIdx.x, kt = blockIdx.y;
  int r0 = rt * 64;
  // load phase: thread t, step s: k_l = t/16 + 16s, cols c..c+3
  int c = (t & 15) * 4;
  #pragma unroll
  for (int s = 0; s < 4; ++s) {
    int k_l = (t >> 4) + 16 * s;
    int kg = kt * 64 + k_l;
    float v0 = 0.f, v1 = 0.f, v2 = 0.f, v3 = 0.f;
    int r = r0 + c;
    if (kg < NP) {
      if (r + 3 < R3) {
        const float* p = pd + (size_t)kg * R3 + r;
        v0 = p[0]; v1 = p[1]; v2 = p[2]; v3 = p[3];
      } else {
        const float* p = pd + (size_t)kg * R3;
        if (r < R3)     v0 = p[r];
        if (r + 1 < R3) v1 = p[r + 1];
        if (r + 2 < R3) v2 = p[r + 2];
        if (r + 3 < R3) v3 = p[r + 3];
      }
    } else if (kg < NP + LB) {
      int ll = kg - NP;
      int cidx = (ll < 10) ? ll : (290 + ll);
      if (r < R3)     v0 = sd[(size_t)(r) * 350 + cidx];
      if (r + 1 < R3) v1 = sd[(size_t)(r + 1) * 350 + cidx];
      if (r + 2 < R3) v2 = sd[(size_t)(r + 2) * 350 + cidx];
      if (r + 3 < R3) v3 = sd[(size_t)(r + 3) * 350 + cidx];
    }
    float* tp = tile + k_l * 68 + c;
    tp[0] = v0; tp[1] = v1; tp[2] = v2; tp[3] = v3;
  }
  __syncthreads();
  // store phase: thread t: r_l = t/4, k-chunk a = t%4 (16 k each)
  int r_l = t >> 2, a = t & 3;
  unsigned short h[16];
  #pragma unroll
  for (int i = 0; i < 16; ++i) h[i] = f2b(tile[(a * 16 + i) * 68 + r_l]);
  unsigned short* dp = Dtr + (size_t)(r0 + r_l) * KP + kt * 64 + a * 16;
  #pragma unroll
  for (int i = 0; i < 16; ++i) dp[i] = h[i];
}

// ---------------- K2c: Wb[v][64] bf16 from lbs ----------------------------
__global__ __launch_bounds__(256) void k_wb(
    const float* __restrict__ lbs, unsigned short* __restrict__ Wb) {
  int v0 = blockIdx.x * 16;
  for (int idx = threadIdx.x; idx < 1024; idx += 256) {
    int v_l = idx >> 6, k = idx & 63;
    int v = v0 + v_l;
    float val = (k < NJ && v < V) ? lbs[(size_t)v * NJ + k] : 0.f;
    Wb[(size_t)v * 64 + k] = f2b(val);
  }
}

// ---------------- K3: joints + chain + arelb bf16 [b][16n][64k] -----------
__global__ __launch_bounds__(64) void k_chain(
    const float* __restrict__ JS, const float* __restrict__ betas_T,
    const float* __restrict__ rot_ws, unsigned short* __restrict__ arelb,
    float* __restrict__ out) {
  int b = blockIdx.x;
  int lane = threadIdx.x;
  __shared__ float joints_l[165];
  __shared__ float Tl[880];
  __shared__ float A[880];
  for (int idx = lane; idx < 165; idx += 64) {
    float sacc = JS[idx * 61 + 60];  // v_template column
    #pragma unroll
    for (int l = 0; l < LB; ++l) sacc += JS[idx * 61 + l] * betas_T[l * BS + b];
    joints_l[idx] = sacc;
  }
  __syncthreads();
  for (int idx = lane; idx < 880; idx += 64) {
    int j = idx >> 4, e = idx & 15, r = e >> 2, cc = e & 3;
    float val;
    if (r < 3) {
      if (cc < 3) val = rot_ws[((size_t)b * NJ + j) * 9 + r * 3 + cc];
      else {
        int par = PARENTS_d[j];
        val = joints_l[j * 3 + r] - (par >= 0 ? joints_l[par * 3 + r] : 0.f);
      }
    } else val = (cc == 3) ? 1.f : 0.f;
    Tl[idx] = val;
  }
  __syncthreads();
  if (lane < 16) A[lane] = Tl[lane];
  __syncthreads();
  for (int j = 1; j < NJ; ++j) {
    int par = PARENTS_d[j];
    if (lane < 16) {
      int r = lane >> 2, cc = lane & 3;
      float sacc = 0.f;
      #pragma unroll
      for (int k = 0; k < 4; ++k)
        sacc += A[par * 16 + r * 4 + k] * Tl[j * 16 + k * 4 + cc];
      A[j * 16 + lane] = sacc;
    }
    __syncthreads();
  }
  for (int idx = lane; idx < 165; idx += 64) {
    int j = idx / 3, r = idx % 3;
    out[JOFF + (size_t)b * 165 + idx] = A[j * 16 + r * 4 + 3];
  }
  // arelb: n = m*4 + col (m row of 3x4, col 0..3 where col3 = adjusted trans)
  for (int idx = lane; idx < 1024; idx += 64) {
    int n = idx >> 6, k = idx & 63;
    float val = 0.f;
    if (n < 12 && k < NJ) {
      int m = n >> 2, cc = n & 3;
      if (cc < 3) val = A[k * 16 + m * 4 + cc];
      else {
        val = A[k * 16 + m * 4 + 3]
            - (A[k * 16 + m * 4 + 0] * joints_l[k * 3 + 0] +
               A[k * 16 + m * 4 + 1] * joints_l[k * 3 + 1] +
               A[k * 16 + m * 4 + 2] * joints_l[k * 3 + 2]);
      }
    }
    arelb[(size_t)b * 1024 + idx] = f2b(val);
  }
}

// ---------------- K4: MFMA GEMM  out[b][r] = vt[r] + (Ftr @ Dtr^T)[b][r] --
// block: 64 r x 256 b; wave: 64 b (4 m-tiles) x 64 r (4 n-tiles)
__global__ __launch_bounds__(256) void k_gemm(
    const float* __restrict__ vt, const unsigned short* __restrict__ Ftr,
    const unsigned short* __restrict__ Dtr, float* __restrict__ out) {
  int lane = threadIdx.x & 63;
  int wv = threadIdx.x >> 6;
  int l15 = lane & 15, q = lane >> 4;
  int r0 = blockIdx.x * 64;
  int m0 = wv * 64;
  float4_ acc[4][4];
  #pragma unroll
  for (int mt = 0; mt < 4; ++mt)
    #pragma unroll
    for (int nt = 0; nt < 4; ++nt) acc[mt][nt] = (float4_)0.f;

  const unsigned short* aBase[4];
  const unsigned short* bBase[4];
  #pragma unroll
  for (int mt = 0; mt < 4; ++mt)
    aBase[mt] = Ftr + (size_t)(m0 + mt * 16 + l15) * KP + q * 8;
  #pragma unroll
  for (int nt = 0; nt < 4; ++nt)
    bBase[nt] = Dtr + (size_t)(r0 + nt * 16 + l15) * KP + q * 8;

  short8 af[4], bf[4], an[4], bn[4];
  #pragma unroll
  for (int mt = 0; mt < 4; ++mt) af[mt] = *(const short8*)(aBase[mt]);
  #pragma unroll
  for (int nt = 0; nt < 4; ++nt) bf[nt] = *(const short8*)(bBase[nt]);

  #pragma unroll 1
  for (int kk = 0; kk < 18; ++kk) {
    if (kk < 17) {
      int off = (kk + 1) * 32;
      #pragma unroll
      for (int mt = 0; mt < 4; ++mt) an[mt] = *(const short8*)(aBase[mt] + off);
      #pragma unroll
      for (int nt = 0; nt < 4; ++nt) bn[nt] = *(const short8*)(bBase[nt] + off);
    }
    #pragma unroll
    for (int mt = 0; mt < 4; ++mt)
      #pragma unroll
      for (int nt = 0; nt < 4; ++nt)
        acc[mt][nt] = __builtin_amdgcn_mfma_f32_16x16x32_bf16(
            af[mt], bf[nt], acc[mt][nt], 0, 0, 0);
    #pragma unroll
    for (int mt = 0; mt < 4; ++mt) af[mt] = an[mt];
    #pragma unroll
    for (int nt = 0; nt < 4; ++nt) bf[nt] = bn[nt];
  }

  #pragma unroll
  for (int nt = 0; nt < 4; ++nt) {
    int r = r0 + nt * 16 + l15;
    if (r < R3) {
      float vtv = vt[r];
      #pragma unroll
      for (int mt = 0; mt < 4; ++mt) {
        int bb = m0 + mt * 16 + q * 4;
        #pragma unroll
        for (int reg = 0; reg < 4; ++reg)
          out[(size_t)(bb + reg) * R3 + r] = acc[mt][nt][reg] + vtv;
      }
    }
  }
}

// ---------------- K5: MFMA skinning ---------------------------------------
// block: 1 v-tile (16 v) x 64 batches; wave: 16 batches sequential
__global__ __launch_bounds__(256) void k_skin(
    const unsigned short* __restrict__ Wb, const unsigned short* __restrict__ arelb,
    float* __restrict__ out) {
  __shared__ float Tls[4 * 320];
  int lane = threadIdx.x & 63;
  int wv = threadIdx.x >> 6;
  int l15 = lane & 15, q = lane >> 4;
  int v0 = blockIdx.x * 16;
  int bbase = blockIdx.y * 64 + wv * 16;
  float* tb = Tls + wv * 320;

  const unsigned short* wp = Wb + (size_t)(v0 + l15) * 64 + q * 8;
  short8 a0 = *(const short8*)(wp);
  short8 a1 = *(const short8*)(wp + 32);

  int v = v0 + l15;
  int m = q;
  #pragma unroll 1
  for (int bi = 0; bi < 16; ++bi) {
    int b = bbase + bi;
    const unsigned short* bp = arelb + (size_t)b * 1024 + l15 * 64 + q * 8;
    short8 b0 = *(const short8*)(bp);
    short8 b1 = *(const short8*)(bp + 32);
    float4_ acc = (float4_)0.f;
    acc = __builtin_amdgcn_mfma_f32_16x16x32_bf16(a0, b0, acc, 0, 0, 0);
    acc = __builtin_amdgcn_mfma_f32_16x16x32_bf16(a1, b1, acc, 0, 0, 0);
    // T[v_l][n]: v_l = q*4+reg, n = l15 ; store [v][n] pitch 20
    #pragma unroll
    for (int reg = 0; reg < 4; ++reg) tb[(q * 4 + reg) * 20 + l15] = acc[reg];
    __builtin_amdgcn_s_waitcnt(0);  // lgkmcnt(0): wave-internal LDS ordering
    // read T[v=l15][4m..4m+3]
    float4_ T4 = *(float4_*)(&tb[l15 * 20 + m * 4]);
    if (m < 3 && v < V) {
      float* vp = out + (size_t)b * R3 + v * 3;
      float x = vp[0], y = vp[1], z = vp[2];
      float val = T4[0] * x + T4[1] * y + T4[2] * z + T4[3];
      vp[m] = val;
    }
  }
}

extern "C" void kernel_launch(void* const* d_in, const int* in_sizes, int n_in,
                              void* d_out, int out_size, void* d_ws, size_t ws_size,
                              hipStream_t stream) {
  const float* pose = (const float*)d_in[0];
  const float* shp  = (const float*)d_in[1];
  const float* expr = (const float*)d_in[2];
  const float* go   = (const float*)d_in[3];
  const float* vt   = (const float*)d_in[4];
  const float* sd   = (const float*)d_in[5];
  const float* pd   = (const float*)d_in[6];
  const float* jr   = (const float*)d_in[7];
  const float* lbs  = (const float*)d_in[8];
  float* out = (float*)d_out;
  float* ws  = (float*)d_ws;

  float* betas_T       = ws;                        // 15360 fl
  float* rot_ws        = ws + 15360;                // 126720 fl
  float* JS            = ws + 142080;               // 10080 fl
  unsigned short* Ftr  = (unsigned short*)(ws + 152160);   // 256*576 us = 73728 fl
  unsigned short* arelb= (unsigned short*)(ws + 225888);   // 256*1024 us = 131072 fl
  unsigned short* Wb   = (unsigned short*)(ws + 356960);   // 10480*64 us = 335360 fl
  float* JregT         = ws + 692320;               // 10475*56 = 586600 fl
  unsigned short* Dtr  = (unsigned short*)(ws + 1278920);  // 31488*576 us = 9068544 fl
  // total ~41.4 MB of d_ws

  hipMemsetAsync(JS, 0, 10080 * sizeof(float), stream);
  k_pose<<<NJ + 1, 256, 0, stream>>>(pose, shp, expr, go, rot_ws, Ftr, betas_T);
  k_tr<<<41, 256, 0, stream>>>(jr, JregT);
  k_js2<<<dim3(3, 32), 256, 0, stream>>>(JregT, sd, vt, JS);
  k_trD<<<dim3(492, 9), 256, 0, stream>>>(pd, sd, Dtr);
  k_wb<<<655, 256, 0, stream>>>(lbs, Wb);
  k_chain<<<BS, 64, 0, stream>>>(JS, betas_T, rot_ws, arelb, out);
  k_gemm<<<492, 256, 0, stream>>>(vt, Ftr, Dtr, out);
  k_skin<<<dim3(655, 4), 256, 0, stream>>>(Wb, arelb, out);
}

// Round 4
// 337.611 us; speedup vs baseline: 2.4088x; 1.2364x over previous
//
#include <hip/hip_runtime.h>
#include <math.h>

#define BS 256
#define V 10475
#define NJ 55
#define R3 31425      // V*3
#define NP 486        // 54*9
#define LB 60         // effective betas (10 shape + 50 expression)
#define KP 576        // padded K (486 pose + 60 shape)
#define VK 10496      // V padded to mult of 128 (82*128)
#define JOFF 8044800  // BS*R3 — joints output offset

typedef __attribute__((ext_vector_type(8))) short short8;
typedef __attribute__((ext_vector_type(4))) float float4_;

__device__ const int PARENTS_d[NJ] = {
  -1, 0, 0, 0, 1, 2, 3, 4, 5, 6, 7, 8, 9, 9, 9, 12, 13, 14, 16, 17, 18, 19,
  15, 15, 15, 20, 25, 26, 20, 28, 29, 20, 31, 32, 20, 34, 35, 20, 37, 38,
  21, 40, 41, 21, 43, 44, 21, 46, 47, 21, 49, 50, 21, 52, 53
};

__device__ __forceinline__ unsigned short f2b(float f) {
  unsigned int u = __float_as_uint(f);
  unsigned int r = (u + 0x7FFFu + ((u >> 16) & 1u)) >> 16;
  return (unsigned short)r;
}

// ---------------- K1: rodrigues + Ftr bf16 [b][576] + betas_T fp32 --------
__global__ __launch_bounds__(256) void k_pose(
    const float* __restrict__ pose, const float* __restrict__ shp,
    const float* __restrict__ expr, const float* __restrict__ go,
    float* __restrict__ rot_ws, unsigned short* __restrict__ Ftr,
    float* __restrict__ betas_T) {
  int b = threadIdx.x;
  int j = blockIdx.x;
  if (j == NJ) {  // betas block: Ftr rows 486..575 + betas_T
    #pragma unroll
    for (int l = 0; l < 10; ++l) {
      float v = shp[b * 10 + l];
      betas_T[l * BS + b] = v;
      Ftr[(size_t)b * KP + NP + l] = f2b(v);
    }
    #pragma unroll
    for (int l = 0; l < 50; ++l) {
      float v = expr[b * 50 + l];
      betas_T[(10 + l) * BS + b] = v;
      Ftr[(size_t)b * KP + NP + 10 + l] = f2b(v);
    }
    #pragma unroll
    for (int l = NP + LB; l < KP; ++l) Ftr[(size_t)b * KP + l] = 0;
    return;
  }
  float rx, ry, rz;
  if (j == 0) { rx = go[0]; ry = go[1]; rz = go[2]; }
  else if (j == 23 || j == 24) { rx = 0.f; ry = 0.f; rz = 0.f; }
  else {
    int src = (j <= 21) ? j : (j == 22 ? 52 : j - 3);
    const float* p = pose + ((size_t)b * 53 + src) * 3;
    rx = p[0]; ry = p[1]; rz = p[2];
  }
  float sx = rx + 1e-8f, sy = ry + 1e-8f, sz = rz + 1e-8f;
  float ang = sqrtf(sx * sx + sy * sy + sz * sz);
  float inv = 1.f / ang;
  float x = rx * inv, y = ry * inv, z = rz * inv;
  float s = sinf(ang), c = cosf(ang), C = 1.f - c;
  float R[9];
  R[0] = 1.f - C * (y * y + z * z);
  R[1] = -s * z + C * x * y;
  R[2] =  s * y + C * x * z;
  R[3] =  s * z + C * x * y;
  R[4] = 1.f - C * (x * x + z * z);
  R[5] = -s * x + C * y * z;
  R[6] = -s * y + C * x * z;
  R[7] =  s * x + C * y * z;
  R[8] = 1.f - C * (x * x + y * y);
  float* rw = rot_ws + ((size_t)b * NJ + j) * 9;
  #pragma unroll
  for (int e = 0; e < 9; ++e) rw[e] = R[e];
  if (j >= 1) {
    int pb = (j - 1) * 9;
    #pragma unroll
    for (int e = 0; e < 9; ++e)
      Ftr[(size_t)b * KP + pb + e] =
          f2b(R[e] - ((e == 0 || e == 4 || e == 8) ? 1.f : 0.f));
  }
}

// ---------------- K1b: Jregb[64][VK] bf16 = pad(Jreg) ---------------------
__global__ __launch_bounds__(256) void k_jregb(
    const float* __restrict__ Jreg, unsigned short* __restrict__ Jregb) {
  size_t idx = (size_t)blockIdx.x * 256 + threadIdx.x;  // 64*VK total
  int j = (int)(idx / VK);
  int v = (int)(idx - (size_t)j * VK);
  float val = (j < NJ && v < V) ? Jreg[(size_t)j * V + v] : 0.f;
  Jregb[idx] = f2b(val);
}

// ---------------- K1c: XbT[192][VK] bf16 — sd live cols + vt, v-contig ----
__global__ __launch_bounds__(256) void k_trX(
    const float* __restrict__ sd, const float* __restrict__ vt,
    unsigned short* __restrict__ XbT) {
  __shared__ float tile[192][65];
  int t = threadIdx.x;
  int v0 = blockIdx.x * 64;
  #pragma unroll 1
  for (int c = 0; c < 3; ++c) {
    for (int idx = t; idx < 3840; idx += 256) {
      int v_l = idx / 60, col = idx - v_l * 60;
      int v = v0 + v_l;
      int cidx = (col < 10) ? col : 290 + col;
      float val = (v < V) ? sd[((size_t)v * 3 + c) * 350 + cidx] : 0.f;
      tile[c * 64 + col][v_l] = val;
    }
  }
  // rows l=60 (vt) and 61..63 (zero)
  for (int idx = t; idx < 768; idx += 256) {
    int v_l = idx & 63, rr = idx >> 6;
    int c = rr >> 2, l = 60 + (rr & 3);
    int v = v0 + v_l;
    float val = (l == 60 && v < V) ? vt[(size_t)v * 3 + c] : 0.f;
    tile[c * 64 + l][v_l] = val;
  }
  __syncthreads();
  for (int idx = t; idx < 192 * 64; idx += 256) {
    int cl = idx >> 6, v_l = idx & 63;
    XbT[(size_t)cl * VK + v0 + v_l] = f2b(tile[cl][v_l]);
  }
}

// ---------------- K2: JS via MFMA — M=64(j) N=192(3c*64) K=VK -------------
// 82 blocks x 128 K each; wave = m-tile; fp32 atomicAdd into JS[165][61]
__global__ __launch_bounds__(256) void k_jsm(
    const unsigned short* __restrict__ Jregb,
    const unsigned short* __restrict__ XbT, float* __restrict__ JS) {
  int lane = threadIdx.x & 63;
  int wv = threadIdx.x >> 6;
  int l15 = lane & 15, q = lane >> 4;
  int k0 = blockIdx.x * 128;
  const unsigned short* ap = Jregb + (size_t)(wv * 16 + l15) * VK + k0 + q * 8;
  float4_ acc[12];
  #pragma unroll
  for (int nt = 0; nt < 12; ++nt) acc[nt] = (float4_)0.f;
  #pragma unroll
  for (int ks = 0; ks < 4; ++ks) {
    short8 a = *(const short8*)(ap + ks * 32);
    #pragma unroll
    for (int nt = 0; nt < 12; ++nt) {
      const unsigned short* bp =
          XbT + (size_t)(nt * 16 + l15) * VK + k0 + ks * 32 + q * 8;
      short8 b = *(const short8*)bp;
      acc[nt] = __builtin_amdgcn_mfma_f32_16x16x32_bf16(a, b, acc[nt], 0, 0, 0);
    }
  }
  #pragma unroll
  for (int nt = 0; nt < 12; ++nt) {
    int cl = nt * 16 + l15;
    int c = cl >> 6, l = cl & 63;
    if (l < 61) {
      #pragma unroll
      for (int reg = 0; reg < 4; ++reg) {
        int jj = wv * 16 + q * 4 + reg;
        if (jj < NJ)
          atomicAdd(&JS[((size_t)jj * 3 + c) * 61 + l], acc[nt][reg]);
      }
    }
  }
}

// ---------------- K2b: Dtr[r][576] bf16 = transpose([pd ; sd_slice]) ------
__global__ __launch_bounds__(256) void k_trD(
    const float* __restrict__ pd, const float* __restrict__ sd,
    unsigned short* __restrict__ Dtr) {
  __shared__ float tile[64 * 68];
  int t = threadIdx.x;
  int rt = blockIdx.x, kt = blockIdx.y;
  int r0 = rt * 64;
  int c = (t & 15) * 4;
  #pragma unroll
  for (int s = 0; s < 4; ++s) {
    int k_l = (t >> 4) + 16 * s;
    int kg = kt * 64 + k_l;
    float v0 = 0.f, v1 = 0.f, v2 = 0.f, v3 = 0.f;
    int r = r0 + c;
    if (kg < NP) {
      if (r + 3 < R3) {
        const float* p = pd + (size_t)kg * R3 + r;
        v0 = p[0]; v1 = p[1]; v2 = p[2]; v3 = p[3];
      } else {
        const float* p = pd + (size_t)kg * R3;
        if (r < R3)     v0 = p[r];
        if (r + 1 < R3) v1 = p[r + 1];
        if (r + 2 < R3) v2 = p[r + 2];
        if (r + 3 < R3) v3 = p[r + 3];
      }
    } else if (kg < NP + LB) {
      int ll = kg - NP;
      int cidx = (ll < 10) ? ll : (290 + ll);
      if (r < R3)     v0 = sd[(size_t)(r) * 350 + cidx];
      if (r + 1 < R3) v1 = sd[(size_t)(r + 1) * 350 + cidx];
      if (r + 2 < R3) v2 = sd[(size_t)(r + 2) * 350 + cidx];
      if (r + 3 < R3) v3 = sd[(size_t)(r + 3) * 350 + cidx];
    }
    float* tp = tile + k_l * 68 + c;
    tp[0] = v0; tp[1] = v1; tp[2] = v2; tp[3] = v3;
  }
  __syncthreads();
  int r_l = t >> 2, a = t & 3;
  unsigned short h[16];
  #pragma unroll
  for (int i = 0; i < 16; ++i) h[i] = f2b(tile[(a * 16 + i) * 68 + r_l]);
  unsigned short* dp = Dtr + (size_t)(r0 + r_l) * KP + kt * 64 + a * 16;
  #pragma unroll
  for (int i = 0; i < 16; ++i) dp[i] = h[i];
}

// ---------------- K2c: Wb[v][64] bf16 from lbs ----------------------------
__global__ __launch_bounds__(256) void k_wb(
    const float* __restrict__ lbs, unsigned short* __restrict__ Wb) {
  int v0 = blockIdx.x * 16;
  for (int idx = threadIdx.x; idx < 1024; idx += 256) {
    int v_l = idx >> 6, k = idx & 63;
    int v = v0 + v_l;
    float val = (k < NJ && v < V) ? lbs[(size_t)v * NJ + k] : 0.f;
    Wb[(size_t)v * 64 + k] = f2b(val);
  }
}

// ---------------- K3: joints + chain + arelb bf16 [b][16n][64k] -----------
__global__ __launch_bounds__(64) void k_chain(
    const float* __restrict__ JS, const float* __restrict__ betas_T,
    const float* __restrict__ rot_ws, unsigned short* __restrict__ arelb,
    float* __restrict__ out) {
  int b = blockIdx.x;
  int lane = threadIdx.x;
  __shared__ float joints_l[165];
  __shared__ float Tl[880];
  __shared__ float A[880];
  for (int idx = lane; idx < 165; idx += 64) {
    float sacc = JS[idx * 61 + 60];  // v_template column
    #pragma unroll
    for (int l = 0; l < LB; ++l) sacc += JS[idx * 61 + l] * betas_T[l * BS + b];
    joints_l[idx] = sacc;
  }
  __syncthreads();
  for (int idx = lane; idx < 880; idx += 64) {
    int j = idx >> 4, e = idx & 15, r = e >> 2, cc = e & 3;
    float val;
    if (r < 3) {
      if (cc < 3) val = rot_ws[((size_t)b * NJ + j) * 9 + r * 3 + cc];
      else {
        int par = PARENTS_d[j];
        val = joints_l[j * 3 + r] - (par >= 0 ? joints_l[par * 3 + r] : 0.f);
      }
    } else val = (cc == 3) ? 1.f : 0.f;
    Tl[idx] = val;
  }
  __syncthreads();
  if (lane < 16) A[lane] = Tl[lane];
  __syncthreads();
  for (int j = 1; j < NJ; ++j) {
    int par = PARENTS_d[j];
    if (lane < 16) {
      int r = lane >> 2, cc = lane & 3;
      float sacc = 0.f;
      #pragma unroll
      for (int k = 0; k < 4; ++k)
        sacc += A[par * 16 + r * 4 + k] * Tl[j * 16 + k * 4 + cc];
      A[j * 16 + lane] = sacc;
    }
    __syncthreads();
  }
  for (int idx = lane; idx < 165; idx += 64) {
    int j = idx / 3, r = idx % 3;
    out[JOFF + (size_t)b * 165 + idx] = A[j * 16 + r * 4 + 3];
  }
  for (int idx = lane; idx < 1024; idx += 64) {
    int n = idx >> 6, k = idx & 63;
    float val = 0.f;
    if (n < 12 && k < NJ) {
      int m = n >> 2, cc = n & 3;
      if (cc < 3) val = A[k * 16 + m * 4 + cc];
      else {
        val = A[k * 16 + m * 4 + 3]
            - (A[k * 16 + m * 4 + 0] * joints_l[k * 3 + 0] +
               A[k * 16 + m * 4 + 1] * joints_l[k * 3 + 1] +
               A[k * 16 + m * 4 + 2] * joints_l[k * 3 + 2]);
      }
    }
    arelb[(size_t)b * 1024 + idx] = f2b(val);
  }
}

// ---------------- K4: MFMA GEMM  out[b][r] = vt[r] + (Ftr @ Dtr^T)[b][r] --
__global__ __launch_bounds__(256) void k_gemm(
    const float* __restrict__ vt, const unsigned short* __restrict__ Ftr,
    const unsigned short* __restrict__ Dtr, float* __restrict__ out) {
  int lane = threadIdx.x & 63;
  int wv = threadIdx.x >> 6;
  int l15 = lane & 15, q = lane >> 4;
  int r0 = blockIdx.x * 64;
  int m0 = wv * 64;
  float4_ acc[4][4];
  #pragma unroll
  for (int mt = 0; mt < 4; ++mt)
    #pragma unroll
    for (int nt = 0; nt < 4; ++nt) acc[mt][nt] = (float4_)0.f;

  const unsigned short* aBase[4];
  const unsigned short* bBase[4];
  #pragma unroll
  for (int mt = 0; mt < 4; ++mt)
    aBase[mt] = Ftr + (size_t)(m0 + mt * 16 + l15) * KP + q * 8;
  #pragma unroll
  for (int nt = 0; nt < 4; ++nt)
    bBase[nt] = Dtr + (size_t)(r0 + nt * 16 + l15) * KP + q * 8;

  short8 af[4], bf[4], an[4], bn[4];
  #pragma unroll
  for (int mt = 0; mt < 4; ++mt) af[mt] = *(const short8*)(aBase[mt]);
  #pragma unroll
  for (int nt = 0; nt < 4; ++nt) bf[nt] = *(const short8*)(bBase[nt]);

  #pragma unroll 1
  for (int kk = 0; kk < 18; ++kk) {
    if (kk < 17) {
      int off = (kk + 1) * 32;
      #pragma unroll
      for (int mt = 0; mt < 4; ++mt) an[mt] = *(const short8*)(aBase[mt] + off);
      #pragma unroll
      for (int nt = 0; nt < 4; ++nt) bn[nt] = *(const short8*)(bBase[nt] + off);
    }
    #pragma unroll
    for (int mt = 0; mt < 4; ++mt)
      #pragma unroll
      for (int nt = 0; nt < 4; ++nt)
        acc[mt][nt] = __builtin_amdgcn_mfma_f32_16x16x32_bf16(
            af[mt], bf[nt], acc[mt][nt], 0, 0, 0);
    #pragma unroll
    for (int mt = 0; mt < 4; ++mt) af[mt] = an[mt];
    #pragma unroll
    for (int nt = 0; nt < 4; ++nt) bf[nt] = bn[nt];
  }

  #pragma unroll
  for (int nt = 0; nt < 4; ++nt) {
    int r = r0 + nt * 16 + l15;
    if (r < R3) {
      float vtv = vt[r];
      #pragma unroll
      for (int mt = 0; mt < 4; ++mt) {
        int bb = m0 + mt * 16 + q * 4;
        #pragma unroll
        for (int reg = 0; reg < 4; ++reg)
          out[(size_t)(bb + reg) * R3 + r] = acc[mt][nt][reg] + vtv;
      }
    }
  }
}

// ---------------- K5: MFMA skinning ---------------------------------------
__global__ __launch_bounds__(256) void k_skin(
    const unsigned short* __restrict__ Wb, const unsigned short* __restrict__ arelb,
    float* __restrict__ out) {
  __shared__ float Tls[4 * 320];
  int lane = threadIdx.x & 63;
  int wv = threadIdx.x >> 6;
  int l15 = lane & 15, q = lane >> 4;
  int v0 = blockIdx.x * 16;
  int bbase = blockIdx.y * 64 + wv * 16;
  float* tb = Tls + wv * 320;

  const unsigned short* wp = Wb + (size_t)(v0 + l15) * 64 + q * 8;
  short8 a0 = *(const short8*)(wp);
  short8 a1 = *(const short8*)(wp + 32);

  int v = v0 + l15;
  int m = q;
  #pragma unroll 1
  for (int bi = 0; bi < 16; ++bi) {
    int b = bbase + bi;
    const unsigned short* bp = arelb + (size_t)b * 1024 + l15 * 64 + q * 8;
    short8 b0 = *(const short8*)(bp);
    short8 b1 = *(const short8*)(bp + 32);
    float4_ acc = (float4_)0.f;
    acc = __builtin_amdgcn_mfma_f32_16x16x32_bf16(a0, b0, acc, 0, 0, 0);
    acc = __builtin_amdgcn_mfma_f32_16x16x32_bf16(a1, b1, acc, 0, 0, 0);
    #pragma unroll
    for (int reg = 0; reg < 4; ++reg) tb[(q * 4 + reg) * 20 + l15] = acc[reg];
    __builtin_amdgcn_s_waitcnt(0);  // lgkmcnt(0): wave-internal LDS ordering
    float4_ T4 = *(float4_*)(&tb[l15 * 20 + m * 4]);
    if (m < 3 && v < V) {
      float* vp = out + (size_t)b * R3 + v * 3;
      float x = vp[0], y = vp[1], z = vp[2];
      float val = T4[0] * x + T4[1] * y + T4[2] * z + T4[3];
      vp[m] = val;
    }
  }
}

extern "C" void kernel_launch(void* const* d_in, const int* in_sizes, int n_in,
                              void* d_out, int out_size, void* d_ws, size_t ws_size,
                              hipStream_t stream) {
  const float* pose = (const float*)d_in[0];
  const float* shp  = (const float*)d_in[1];
  const float* expr = (const float*)d_in[2];
  const float* go   = (const float*)d_in[3];
  const float* vt   = (const float*)d_in[4];
  const float* sd   = (const float*)d_in[5];
  const float* pd   = (const float*)d_in[6];
  const float* jr   = (const float*)d_in[7];
  const float* lbs  = (const float*)d_in[8];
  float* out = (float*)d_out;
  float* ws  = (float*)d_ws;

  float* betas_T        = ws;                                 // 15360 fl
  float* rot_ws         = ws + 15360;                         // 126720 fl
  float* JS             = ws + 142080;                        // 10080 fl
  unsigned short* Ftr   = (unsigned short*)(ws + 152160);     // 73728 fl
  unsigned short* arelb = (unsigned short*)(ws + 225888);     // 131072 fl
  unsigned short* Wb    = (unsigned short*)(ws + 356960);     // 335360 fl
  unsigned short* Jregb = (unsigned short*)(ws + 692320);     // 64*VK us = 335872 fl
  unsigned short* XbT   = (unsigned short*)(ws + 1028192);    // 192*VK us = 1007616 fl
  unsigned short* Dtr   = (unsigned short*)(ws + 2035808);    // 31488*576 us = 9068544 fl
  // total ~44.4 MB of d_ws

  hipMemsetAsync(JS, 0, 10080 * sizeof(float), stream);
  k_pose<<<NJ + 1, 256, 0, stream>>>(pose, shp, expr, go, rot_ws, Ftr, betas_T);
  k_jregb<<<(64 * VK) / 256, 256, 0, stream>>>(jr, Jregb);
  k_trX<<<VK / 64, 256, 0, stream>>>(sd, vt, XbT);
  k_jsm<<<VK / 128, 256, 0, stream>>>(Jregb, XbT, JS);
  k_trD<<<dim3(492, 9), 256, 0, stream>>>(pd, sd, Dtr);
  k_wb<<<655, 256, 0, stream>>>(lbs, Wb);
  k_chain<<<BS, 64, 0, stream>>>(JS, betas_T, rot_ws, arelb, out);
  k_gemm<<<492, 256, 0, stream>>>(vt, Ftr, Dtr, out);
  k_skin<<<dim3(655, 4), 256, 0, stream>>>(Wb, arelb, out);
}

// Round 5
// 311.357 us; speedup vs baseline: 2.6119x; 1.0843x over previous
//
#include <hip/hip_runtime.h>
#include <math.h>

#define BS 256
#define V 10475
#define NJ 55
#define R3 31425      // V*3
#define NP 486        // 54*9
#define LB 60         // effective betas (10 shape + 50 expression)
#define KP 576        // padded K (486 pose + 60 shape)
#define VK 10496      // V padded to mult of 128 (82*128)
#define JOFF 8044800  // BS*R3 — joints output offset
#define DSP 66        // LDS staging pitch (floats) — 2-way-free frag reads

typedef __attribute__((ext_vector_type(8))) short short8;
typedef __attribute__((ext_vector_type(4))) float float4_;

__device__ const int PARENTS_d[NJ] = {
  -1, 0, 0, 0, 1, 2, 3, 4, 5, 6, 7, 8, 9, 9, 9, 12, 13, 14, 16, 17, 18, 19,
  15, 15, 15, 20, 25, 26, 20, 28, 29, 20, 31, 32, 20, 34, 35, 20, 37, 38,
  21, 40, 41, 21, 43, 44, 21, 46, 47, 21, 49, 50, 21, 52, 53
};

__device__ __forceinline__ unsigned short f2b(float f) {
  unsigned int u = __float_as_uint(f);
  unsigned int r = (u + 0x7FFFu + ((u >> 16) & 1u)) >> 16;
  return (unsigned short)r;
}

// ---------------- K1: rodrigues + Ftr bf16 [b][576] + betas_T fp32 --------
__global__ __launch_bounds__(256) void k_pose(
    const float* __restrict__ pose, const float* __restrict__ shp,
    const float* __restrict__ expr, const float* __restrict__ go,
    float* __restrict__ rot_ws, unsigned short* __restrict__ Ftr,
    float* __restrict__ betas_T) {
  int b = threadIdx.x;
  int j = blockIdx.x;
  if (j == NJ) {  // betas block: Ftr rows 486..575 + betas_T
    #pragma unroll
    for (int l = 0; l < 10; ++l) {
      float v = shp[b * 10 + l];
      betas_T[l * BS + b] = v;
      Ftr[(size_t)b * KP + NP + l] = f2b(v);
    }
    #pragma unroll
    for (int l = 0; l < 50; ++l) {
      float v = expr[b * 50 + l];
      betas_T[(10 + l) * BS + b] = v;
      Ftr[(size_t)b * KP + NP + 10 + l] = f2b(v);
    }
    #pragma unroll
    for (int l = NP + LB; l < KP; ++l) Ftr[(size_t)b * KP + l] = 0;
    return;
  }
  float rx, ry, rz;
  if (j == 0) { rx = go[0]; ry = go[1]; rz = go[2]; }
  else if (j == 23 || j == 24) { rx = 0.f; ry = 0.f; rz = 0.f; }
  else {
    int src = (j <= 21) ? j : (j == 22 ? 52 : j - 3);
    const float* p = pose + ((size_t)b * 53 + src) * 3;
    rx = p[0]; ry = p[1]; rz = p[2];
  }
  float sx = rx + 1e-8f, sy = ry + 1e-8f, sz = rz + 1e-8f;
  float ang = sqrtf(sx * sx + sy * sy + sz * sz);
  float inv = 1.f / ang;
  float x = rx * inv, y = ry * inv, z = rz * inv;
  float s = sinf(ang), c = cosf(ang), C = 1.f - c;
  float R[9];
  R[0] = 1.f - C * (y * y + z * z);
  R[1] = -s * z + C * x * y;
  R[2] =  s * y + C * x * z;
  R[3] =  s * z + C * x * y;
  R[4] = 1.f - C * (x * x + z * z);
  R[5] = -s * x + C * y * z;
  R[6] = -s * y + C * x * z;
  R[7] =  s * x + C * y * z;
  R[8] = 1.f - C * (x * x + y * y);
  float* rw = rot_ws + ((size_t)b * NJ + j) * 9;
  #pragma unroll
  for (int e = 0; e < 9; ++e) rw[e] = R[e];
  if (j >= 1) {
    int pb = (j - 1) * 9;
    #pragma unroll
    for (int e = 0; e < 9; ++e)
      Ftr[(size_t)b * KP + pb + e] =
          f2b(R[e] - ((e == 0 || e == 4 || e == 8) ? 1.f : 0.f));
  }
}

// ---------------- K1b: Jregb[64][VK] bf16 = pad(Jreg) ---------------------
__global__ __launch_bounds__(256) void k_jregb(
    const float* __restrict__ Jreg, unsigned short* __restrict__ Jregb) {
  size_t idx = (size_t)blockIdx.x * 256 + threadIdx.x;  // 64*VK total
  int j = (int)(idx / VK);
  int v = (int)(idx - (size_t)j * VK);
  float val = (j < NJ && v < V) ? Jreg[(size_t)j * V + v] : 0.f;
  Jregb[idx] = f2b(val);
}

// ---------------- K1c: XbT[192][VK] bf16 — sd live cols + vt, v-contig ----
__global__ __launch_bounds__(256) void k_trX(
    const float* __restrict__ sd, const float* __restrict__ vt,
    unsigned short* __restrict__ XbT) {
  __shared__ float tile[192][65];
  int t = threadIdx.x;
  int v0 = blockIdx.x * 64;
  #pragma unroll 1
  for (int c = 0; c < 3; ++c) {
    for (int idx = t; idx < 3840; idx += 256) {
      int v_l = idx / 60, col = idx - v_l * 60;
      int v = v0 + v_l;
      int cidx = (col < 10) ? col : 290 + col;
      float val = (v < V) ? sd[((size_t)v * 3 + c) * 350 + cidx] : 0.f;
      tile[c * 64 + col][v_l] = val;
    }
  }
  for (int idx = t; idx < 768; idx += 256) {
    int v_l = idx & 63, rr = idx >> 6;
    int c = rr >> 2, l = 60 + (rr & 3);
    int v = v0 + v_l;
    float val = (l == 60 && v < V) ? vt[(size_t)v * 3 + c] : 0.f;
    tile[c * 64 + l][v_l] = val;
  }
  __syncthreads();
  for (int idx = t; idx < 192 * 64; idx += 256) {
    int cl = idx >> 6, v_l = idx & 63;
    XbT[(size_t)cl * VK + v0 + v_l] = f2b(tile[cl][v_l]);
  }
}

// ---------------- K2: JS via MFMA — M=64(j) N=192(3c*64) K=VK -------------
__global__ __launch_bounds__(256) void k_jsm(
    const unsigned short* __restrict__ Jregb,
    const unsigned short* __restrict__ XbT, float* __restrict__ JS) {
  int lane = threadIdx.x & 63;
  int wv = threadIdx.x >> 6;
  int l15 = lane & 15, q = lane >> 4;
  int k0 = blockIdx.x * 128;
  const unsigned short* ap = Jregb + (size_t)(wv * 16 + l15) * VK + k0 + q * 8;
  float4_ acc[12];
  #pragma unroll
  for (int nt = 0; nt < 12; ++nt) acc[nt] = (float4_)0.f;
  #pragma unroll
  for (int ks = 0; ks < 4; ++ks) {
    short8 a = *(const short8*)(ap + ks * 32);
    #pragma unroll
    for (int nt = 0; nt < 12; ++nt) {
      const unsigned short* bp =
          XbT + (size_t)(nt * 16 + l15) * VK + k0 + ks * 32 + q * 8;
      short8 b = *(const short8*)bp;
      acc[nt] = __builtin_amdgcn_mfma_f32_16x16x32_bf16(a, b, acc[nt], 0, 0, 0);
    }
  }
  #pragma unroll
  for (int nt = 0; nt < 12; ++nt) {
    int cl = nt * 16 + l15;
    int c = cl >> 6, l = cl & 63;
    if (l < 61) {
      #pragma unroll
      for (int reg = 0; reg < 4; ++reg) {
        int jj = wv * 16 + q * 4 + reg;
        if (jj < NJ)
          atomicAdd(&JS[((size_t)jj * 3 + c) * 61 + l], acc[nt][reg]);
      }
    }
  }
}

// ---------------- K2c: Wb[v][64] bf16 from lbs (VK rows) ------------------
__global__ __launch_bounds__(256) void k_wb(
    const float* __restrict__ lbs, unsigned short* __restrict__ Wb) {
  int v0 = blockIdx.x * 16;
  for (int idx = threadIdx.x; idx < 1024; idx += 256) {
    int v_l = idx >> 6, k = idx & 63;
    int v = v0 + v_l;
    float val = (k < NJ && v < V) ? lbs[(size_t)v * NJ + k] : 0.f;
    if (v < VK) Wb[(size_t)v * 64 + k] = f2b(val);
  }
}

// ---------------- K3: joints + chain + arelb bf16 [b][16n][64k] -----------
__global__ __launch_bounds__(64) void k_chain(
    const float* __restrict__ JS, const float* __restrict__ betas_T,
    const float* __restrict__ rot_ws, unsigned short* __restrict__ arelb,
    float* __restrict__ out) {
  int b = blockIdx.x;
  int lane = threadIdx.x;
  __shared__ float joints_l[165];
  __shared__ float Tl[880];
  __shared__ float A[880];
  for (int idx = lane; idx < 165; idx += 64) {
    float sacc = JS[idx * 61 + 60];  // v_template column
    #pragma unroll
    for (int l = 0; l < LB; ++l) sacc += JS[idx * 61 + l] * betas_T[l * BS + b];
    joints_l[idx] = sacc;
  }
  __syncthreads();
  for (int idx = lane; idx < 880; idx += 64) {
    int j = idx >> 4, e = idx & 15, r = e >> 2, cc = e & 3;
    float val;
    if (r < 3) {
      if (cc < 3) val = rot_ws[((size_t)b * NJ + j) * 9 + r * 3 + cc];
      else {
        int par = PARENTS_d[j];
        val = joints_l[j * 3 + r] - (par >= 0 ? joints_l[par * 3 + r] : 0.f);
      }
    } else val = (cc == 3) ? 1.f : 0.f;
    Tl[idx] = val;
  }
  __syncthreads();
  if (lane < 16) A[lane] = Tl[lane];
  __syncthreads();
  for (int j = 1; j < NJ; ++j) {
    int par = PARENTS_d[j];
    if (lane < 16) {
      int r = lane >> 2, cc = lane & 3;
      float sacc = 0.f;
      #pragma unroll
      for (int k = 0; k < 4; ++k)
        sacc += A[par * 16 + r * 4 + k] * Tl[j * 16 + k * 4 + cc];
      A[j * 16 + lane] = sacc;
    }
    __syncthreads();
  }
  for (int idx = lane; idx < 165; idx += 64) {
    int j = idx / 3, r = idx % 3;
    out[JOFF + (size_t)b * 165 + idx] = A[j * 16 + r * 4 + 3];
  }
  for (int idx = lane; idx < 1024; idx += 64) {
    int n = idx >> 6, k = idx & 63;
    float val = 0.f;
    if (n < 12 && k < NJ) {
      int m = n >> 2, cc = n & 3;
      if (cc < 3) val = A[k * 16 + m * 4 + cc];
      else {
        val = A[k * 16 + m * 4 + 3]
            - (A[k * 16 + m * 4 + 0] * joints_l[k * 3 + 0] +
               A[k * 16 + m * 4 + 1] * joints_l[k * 3 + 1] +
               A[k * 16 + m * 4 + 2] * joints_l[k * 3 + 2]);
      }
    }
    arelb[(size_t)b * 1024 + idx] = f2b(val);
  }
}

// ---------------- K4: fused GEMM — stages pd/sd fp32 tiles in LDS ---------
// out[b][r] = vt[r] + sum_k Ftr[b][k] * D[k][r];  D = [pd(486); sd cols(60); 0]
// block: 64 r x 256 b; K-loop: 18 chunks of 32, double-buffered LDS
__global__ __launch_bounds__(256) void k_gemm(
    const float* __restrict__ vt, const float* __restrict__ sd,
    const float* __restrict__ pd, const unsigned short* __restrict__ Ftr,
    float* __restrict__ out) {
  __shared__ float dsb[2][32 * DSP];
  int t = threadIdx.x;
  int lane = t & 63, wv = t >> 6;
  int l15 = lane & 15, q = lane >> 4;
  int r0 = blockIdx.x * 64;
  int m0 = wv * 64;
  int k_l = t >> 3;            // staging row 0..31
  int c8 = (t & 7) * 8;        // staging col group
  bool full = (r0 + 64 <= R3);

  float4_ acc[4][4];
  #pragma unroll
  for (int mt = 0; mt < 4; ++mt)
    #pragma unroll
    for (int nt = 0; nt < 4; ++nt) acc[mt][nt] = (float4_)0.f;

  const unsigned short* aBase[4];
  #pragma unroll
  for (int mt = 0; mt < 4; ++mt)
    aBase[mt] = Ftr + (size_t)(m0 + mt * 16 + l15) * KP + q * 8;

  // ---- stage chunk 0 ----
  {
    int kg = k_l;  // chunk 0: all pd
    float* dp = &dsb[0][k_l * DSP + c8];
    if (full) {
      const float* p = pd + (size_t)kg * R3 + r0 + c8;
      #pragma unroll
      for (int i = 0; i < 8; ++i) dp[i] = p[i];
    } else {
      #pragma unroll
      for (int i = 0; i < 8; ++i) {
        int r = r0 + c8 + i;
        dp[i] = (r < R3) ? pd[(size_t)kg * R3 + r] : 0.f;
      }
    }
  }
  __syncthreads();

  #pragma unroll 1
  for (int c = 0; c < 18; ++c) {
    int cur = c & 1;
    // ---- issue next chunk's global loads ----
    float sv[8];
    if (c < 17) {
      int kg = (c + 1) * 32 + k_l;
      if (kg < NP) {
        if (full) {
          const float* p = pd + (size_t)kg * R3 + r0 + c8;
          #pragma unroll
          for (int i = 0; i < 8; ++i) sv[i] = p[i];
        } else {
          #pragma unroll
          for (int i = 0; i < 8; ++i) {
            int r = r0 + c8 + i;
            sv[i] = (r < R3) ? pd[(size_t)kg * R3 + r] : 0.f;
          }
        }
      } else if (kg < NP + LB) {
        int ll = kg - NP;
        int cidx = (ll < 10) ? ll : (290 + ll);
        #pragma unroll
        for (int i = 0; i < 8; ++i) {
          int r = r0 + c8 + i;
          sv[i] = (r < R3) ? sd[(size_t)r * 350 + cidx] : 0.f;
        }
      } else {
        #pragma unroll
        for (int i = 0; i < 8; ++i) sv[i] = 0.f;
      }
    }
    // ---- build B frags from LDS (fp32 -> bf16) ----
    short8 bf[4];
    #pragma unroll
    for (int nt = 0; nt < 4; ++nt) {
      unsigned short h[8];
      #pragma unroll
      for (int i = 0; i < 8; ++i)
        h[i] = f2b(dsb[cur][(q * 8 + i) * DSP + nt * 16 + l15]);
      short8 v;
      #pragma unroll
      for (int i = 0; i < 8; ++i) v[i] = (short)h[i];
      bf[nt] = v;
    }
    // ---- A frags (global, L2-resident) ----
    short8 af[4];
    #pragma unroll
    for (int mt = 0; mt < 4; ++mt)
      af[mt] = *(const short8*)(aBase[mt] + c * 32);
    // ---- MFMAs ----
    #pragma unroll
    for (int mt = 0; mt < 4; ++mt)
      #pragma unroll
      for (int nt = 0; nt < 4; ++nt)
        acc[mt][nt] = __builtin_amdgcn_mfma_f32_16x16x32_bf16(
            af[mt], bf[nt], acc[mt][nt], 0, 0, 0);
    // ---- write staged data to the other buffer ----
    if (c < 17) {
      float* dp = &dsb[cur ^ 1][k_l * DSP + c8];
      #pragma unroll
      for (int i = 0; i < 8; ++i) dp[i] = sv[i];
    }
    __syncthreads();
  }

  #pragma unroll
  for (int nt = 0; nt < 4; ++nt) {
    int r = r0 + nt * 16 + l15;
    if (r < R3) {
      float vtv = vt[r];
      #pragma unroll
      for (int mt = 0; mt < 4; ++mt) {
        int bb = m0 + mt * 16 + q * 4;
        #pragma unroll
        for (int reg = 0; reg < 4; ++reg)
          out[(size_t)(bb + reg) * R3 + r] = acc[mt][nt][reg] + vtv;
      }
    }
  }
}

// ---------------- K5: MFMA skinning, LDS-free (operand-swapped) -----------
// A = arelb (m = 12 T-entries), B = W (n = 16 vertices)
// => lane (q,l15) acc = T[v0+l15][4q..4q+3]; lanes q<3 apply directly.
__global__ __launch_bounds__(256) void k_skin(
    const unsigned short* __restrict__ Wb, const unsigned short* __restrict__ arelb,
    float* __restrict__ out) {
  int lane = threadIdx.x & 63;
  int wv = threadIdx.x >> 6;
  int l15 = lane & 15, q = lane >> 4;
  int v = blockIdx.x * 64 + wv * 16 + l15;
  bool vok = (v < V);
  int b0 = blockIdx.y * 16;

  const unsigned short* wp = Wb + (size_t)v * 64 + q * 8;
  short8 w0 = *(const short8*)(wp);
  short8 w1 = *(const short8*)(wp + 32);

  const unsigned short* ap = arelb + (size_t)b0 * 1024 + l15 * 64 + q * 8;
  short8 a0 = *(const short8*)ap;
  short8 a1 = *(const short8*)(ap + 32);

  #pragma unroll 1
  for (int bi = 0; bi < 16; ++bi) {
    int b = b0 + bi;
    float* vp = out + (size_t)b * R3 + v * 3;
    float x = 0.f, y = 0.f, z = 0.f;
    if (vok && q < 3) { x = vp[0]; y = vp[1]; z = vp[2]; }
    short8 na0 = a0, na1 = a1;
    if (bi < 15) {
      const unsigned short* np = arelb + (size_t)(b + 1) * 1024 + l15 * 64 + q * 8;
      na0 = *(const short8*)np;
      na1 = *(const short8*)(np + 32);
    }
    float4_ acc = (float4_)0.f;
    acc = __builtin_amdgcn_mfma_f32_16x16x32_bf16(a0, w0, acc, 0, 0, 0);
    acc = __builtin_amdgcn_mfma_f32_16x16x32_bf16(a1, w1, acc, 0, 0, 0);
    if (vok && q < 3)
      vp[q] = acc[0] * x + acc[1] * y + acc[2] * z + acc[3];
    a0 = na0; a1 = na1;
  }
}

extern "C" void kernel_launch(void* const* d_in, const int* in_sizes, int n_in,
                              void* d_out, int out_size, void* d_ws, size_t ws_size,
                              hipStream_t stream) {
  const float* pose = (const float*)d_in[0];
  const float* shp  = (const float*)d_in[1];
  const float* expr = (const float*)d_in[2];
  const float* go   = (const float*)d_in[3];
  const float* vt   = (const float*)d_in[4];
  const float* sd   = (const float*)d_in[5];
  const float* pd   = (const float*)d_in[6];
  const float* jr   = (const float*)d_in[7];
  const float* lbs  = (const float*)d_in[8];
  float* out = (float*)d_out;
  float* ws  = (float*)d_ws;

  float* betas_T        = ws;                                 // 15360 fl
  float* rot_ws         = ws + 15360;                         // 126720 fl
  float* JS             = ws + 142080;                        // 10080 fl
  unsigned short* Ftr   = (unsigned short*)(ws + 152160);     // 73728 fl
  unsigned short* arelb = (unsigned short*)(ws + 225888);     // 131072 fl
  unsigned short* Wb    = (unsigned short*)(ws + 356960);     // VK*64 us = 335872 fl
  unsigned short* Jregb = (unsigned short*)(ws + 692832);     // 64*VK us = 335872 fl
  unsigned short* XbT   = (unsigned short*)(ws + 1028704);    // 192*VK us = 1007616 fl
  // total ~8.1 MB of d_ws

  hipMemsetAsync(JS, 0, 10080 * sizeof(float), stream);
  k_pose<<<NJ + 1, 256, 0, stream>>>(pose, shp, expr, go, rot_ws, Ftr, betas_T);
  k_jregb<<<(64 * VK) / 256, 256, 0, stream>>>(jr, Jregb);
  k_trX<<<VK / 64, 256, 0, stream>>>(sd, vt, XbT);
  k_jsm<<<VK / 128, 256, 0, stream>>>(Jregb, XbT, JS);
  k_wb<<<VK / 16, 256, 0, stream>>>(lbs, Wb);
  k_chain<<<BS, 64, 0, stream>>>(JS, betas_T, rot_ws, arelb, out);
  k_gemm<<<492, 256, 0, stream>>>(vt, sd, pd, Ftr, out);
  k_skin<<<dim3(164, 16), 256, 0, stream>>>(Wb, arelb, out);
}